// Round 3
// baseline (272.082 us; speedup 1.0000x reference)
//
#include <hip/hip_runtime.h>
#include <hip/hip_bf16.h>

typedef __bf16 bf16_t;
typedef __bf16 bf16x4 __attribute__((ext_vector_type(4)));
typedef __bf16 bf16x8 __attribute__((ext_vector_type(8)));
typedef float f32x16 __attribute__((ext_vector_type(16)));

#define E_DIM 1024
#define SEQ   2048
#define NBATCH 4

// raw barrier with compile-time memory fence (prevents GLL/ds_read crossing)
#define BARR()  asm volatile("s_barrier" ::: "memory")
#define VMC8()  asm volatile("s_waitcnt vmcnt(8)" ::: "memory")

// ---------------- cast f32 -> bf16 (vectorized, 8 elems/thread) ----------------
__global__ __launch_bounds__(256) void k_cast(const float* __restrict__ src,
                                              bf16_t* __restrict__ dst) {
  const int i = (blockIdx.x * 256 + threadIdx.x) * 8;
  const float4 a = *(const float4*)(src + i);
  const float4 b = *(const float4*)(src + i + 4);
  bf16x8 o;
  o[0] = (bf16_t)a.x; o[1] = (bf16_t)a.y; o[2] = (bf16_t)a.z; o[3] = (bf16_t)a.w;
  o[4] = (bf16_t)b.x; o[5] = (bf16_t)b.y; o[6] = (bf16_t)b.z; o[7] = (bf16_t)b.w;
  *(bf16x8*)(dst + i) = o;
}

// =================================================================================
// 128x128 GEMM, C = scale*(A @ B^T) + bias (+residual).  A:[M][K] bf16 (lda),
// B:[N][K] bf16 (ldb), K-contiguous.  256 threads = 4 waves (2x2), per-wave 64x64
// via mfma_f32_32x32x16_bf16 (acc = 4 x f32x16 = 64 VGPR).  BK=64.
// Depth-2 circular LDS buffer (2 x 32KB = 64KB -> 2 blocks/CU for cross-block
// overlap).  Counted vmcnt(8) (full-tile latency cover), raw s_barrier (no
// vmcnt(0) drain), one compiler-scheduled ds_read||MFMA region per K-tile.
// T2 XOR-swizzle: linear GLL dest + inverse-swizzled global source + swizzled read.
// OUTMODE 0: f32 out, 1: bf16 out, 2: bf16 transposed out (Vt[b][col][s]).
// =================================================================================
template <int OUTMODE>
__global__ __launch_bounds__(256, 2) void k_gemm3(
    const bf16_t* __restrict__ A, int lda, long sA,
    const bf16_t* __restrict__ B, int ldb, long sB,
    void* __restrict__ Cv, int ldc, long sC,
    int K, float scale, const float* __restrict__ bias,
    const float* __restrict__ residual, int GM, int GN) {
  extern __shared__ char smem[];
  const int tid  = threadIdx.x;
  const int lane = tid & 63;
  const int wid  = tid >> 6;
  const int wm   = wid >> 1, wn = wid & 1;
  const int hi   = lane >> 5;
  const int l31  = lane & 31;

  // T1: bijective XCD swizzle (grid always a multiple of 8)
  const int nwg  = gridDim.x;
  const int orig = blockIdx.x;
  const int wg   = (orig & 7) * (nwg >> 3) + (orig >> 3);
  const int zz   = wg / (GM * GN);
  const int rm   = wg - zz * (GM * GN);
  const int bm   = rm / GN;
  const int bn   = rm - bm * GN;
  const int brow = bm * 128;
  const int bcol = bn * 128;

  // Staging: tile buffers A[128][64], B[128][64] (16KB each), 4 slices of 4KB.
  // Thread t -> row (t>>3) in slice, 16B at byte (t&7)*16; global source col is
  // inverse-XOR-swizzled so swizzled ds_reads see the right data (rule 21).
  const int colk = ((tid & 7) ^ ((tid >> 3) & 7)) << 3;  // element col 0..56
  const bf16_t* Asrc = A + zz * sA + (long)(brow + (tid >> 3)) * lda + colk;
  const bf16_t* Bsrc = B + zz * sB + (long)(bcol + (tid >> 3)) * ldb + colk;
  const int ldsw = wid << 10;

#define GLL(gaddr, ldsoff)                                                       \
  __builtin_amdgcn_global_load_lds(                                             \
      (const __attribute__((address_space(1))) void*)(gaddr),                   \
      (__attribute__((address_space(3))) void*)(smem + (ldsoff)), 16, 0, 0)

  auto stage = [&](int t, int buf) {
    const long koff = (long)t * 64;
#pragma unroll
    for (int s = 0; s < 4; ++s)
      GLL(Asrc + (long)(s * 32) * lda + koff, buf * 32768 + s * 4096 + ldsw);
#pragma unroll
    for (int s = 0; s < 4; ++s)
      GLL(Bsrc + (long)(s * 32) * ldb + koff, buf * 32768 + 16384 + s * 4096 + ldsw);
  };

  f32x16 acc00 = {}, acc01 = {}, acc10 = {}, acc11 = {};

  const int NT = K >> 6;
  stage(0, 0);
  for (int t = 0; t < NT; ++t) {
    const int c = t & 1;
    const int tn = (t + 1 < NT) ? t + 1 : NT - 1;  // clamped: keeps vmcnt count exact
    stage(tn, c ^ 1);
    VMC8();   // retire tile t's 8 loads (t+1's 8 stay in flight: ~1 tile of cover)
    BARR();   // all waves: buf[c] staged & visible
    {
      const char* Ab = smem + c * 32768;
      const char* Bb = smem + c * 32768 + 16384;
      const int ra = wm * 64 + l31;   // A rows for mf=0 (+32 for mf=1)
      const int rb = wn * 64 + l31;
#pragma unroll
      for (int k = 0; k < 4; ++k) {
        const int cb = (k * 32) + (hi << 4);
        bf16x8 a0 = *(const bf16x8*)(Ab + ra * 128 + (cb ^ ((ra & 7) << 4)));
        bf16x8 a1 = *(const bf16x8*)(Ab + (ra + 32) * 128 + (cb ^ (((ra + 32) & 7) << 4)));
        bf16x8 b0 = *(const bf16x8*)(Bb + rb * 128 + (cb ^ ((rb & 7) << 4)));
        bf16x8 b1 = *(const bf16x8*)(Bb + (rb + 32) * 128 + (cb ^ (((rb + 32) & 7) << 4)));
        acc00 = __builtin_amdgcn_mfma_f32_32x32x16_bf16(a0, b0, acc00, 0, 0, 0);
        acc01 = __builtin_amdgcn_mfma_f32_32x32x16_bf16(a0, b1, acc01, 0, 0, 0);
        acc10 = __builtin_amdgcn_mfma_f32_32x32x16_bf16(a1, b0, acc10, 0, 0, 0);
        acc11 = __builtin_amdgcn_mfma_f32_32x32x16_bf16(a1, b1, acc11, 0, 0, 0);
      }
    }
    BARR();   // all waves done reading buf[c] -> next iter may restage it
  }

  // Epilogue. 32x32 C/D layout (m74/m101): col = lane&31, row = (reg&3) + 8*(reg>>2) + 4*hi
  const int colb = bcol + wn * 64 + l31;
  const int rowb = brow + wm * 64 + (hi << 2);
#pragma unroll
  for (int mf = 0; mf < 2; ++mf) {
#pragma unroll
    for (int nf = 0; nf < 2; ++nf) {
      const f32x16 av = (mf == 0) ? (nf == 0 ? acc00 : acc01) : (nf == 0 ? acc10 : acc11);
      const int colg = colb + nf * 32;
      const float bval = bias ? bias[colg] : 0.0f;
#pragma unroll
      for (int g = 0; g < 4; ++g) {
        const int r0 = rowb + mf * 32 + g * 8;
        if constexpr (OUTMODE == 2) {
          bf16x4 pk;
#pragma unroll
          for (int j = 0; j < 4; ++j) pk[j] = (bf16_t)(av[g * 4 + j] * scale + bval);
          const long bb = (long)(r0 >> 11);
          const int ss = r0 & (SEQ - 1);
          *(bf16x4*)((bf16_t*)Cv + bb * ((long)E_DIM * SEQ) + (long)colg * SEQ + ss) = pk;
        } else {
#pragma unroll
          for (int j = 0; j < 4; ++j) {
            const int r = r0 + j;
            float v = av[g * 4 + j] * scale + bval;
            if (residual) v += residual[(long)r * ldc + colg];
            const long idx = (long)zz * sC + (long)r * ldc + colg;
            if constexpr (OUTMODE == 0) ((float*)Cv)[idx] = v;
            else ((bf16_t*)Cv)[idx] = (bf16_t)v;
          }
        }
      }
    }
  }
#undef GLL
}

// ---------------- row softmax on bf16 scores (2048/row), bf16 P in place --------
__global__ __launch_bounds__(256) void k_softmax_bf(bf16_t* __restrict__ sc) {
  const long row = blockIdx.x;
  bf16_t* rp = sc + row * 2048;
  const int t = threadIdx.x;
  const bf16x8 v = *(const bf16x8*)(rp + t * 8);
  float x[8];
#pragma unroll
  for (int i = 0; i < 8; ++i) x[i] = (float)v[i];
  float mx = x[0];
#pragma unroll
  for (int i = 1; i < 8; ++i) mx = fmaxf(mx, x[i]);
#pragma unroll
  for (int o = 32; o; o >>= 1) mx = fmaxf(mx, __shfl_xor(mx, o));
  __shared__ float redm[4], reds[4];
  const int lane = t & 63, w = t >> 6;
  if (lane == 0) redm[w] = mx;
  __syncthreads();
  mx = fmaxf(fmaxf(redm[0], redm[1]), fmaxf(redm[2], redm[3]));
  float p[8], s = 0.f;
#pragma unroll
  for (int i = 0; i < 8; ++i) { p[i] = __expf(x[i] - mx); s += p[i]; }
#pragma unroll
  for (int o = 32; o; o >>= 1) s += __shfl_xor(s, o);
  if (lane == 0) reds[w] = s;
  __syncthreads();
  const float inv = 1.0f / (reds[0] + reds[1] + reds[2] + reds[3]);
  bf16x8 o8;
#pragma unroll
  for (int i = 0; i < 8; ++i) o8[i] = (bf16_t)(p[i] * inv);
  *(bf16x8*)(rp + t * 8) = o8;
}

// ---------------- layernorm in-place on rows of 1024 f32 ----------------
__global__ __launch_bounds__(256) void k_layernorm(float* __restrict__ out,
                                                   const float* __restrict__ gamma,
                                                   const float* __restrict__ beta) {
  const long row = blockIdx.x;
  float* rp = out + row * 1024;
  const int t = threadIdx.x;
  const float4 v = *(const float4*)(rp + t * 4);
  float s = v.x + v.y + v.z + v.w;
#pragma unroll
  for (int o = 32; o; o >>= 1) s += __shfl_xor(s, o);
  __shared__ float red1[4], red2[4];
  const int lane = t & 63, w = t >> 6;
  if (lane == 0) red1[w] = s;
  __syncthreads();
  const float mu = (red1[0] + red1[1] + red1[2] + red1[3]) * (1.0f / 1024.0f);
  const float d0 = v.x - mu, d1 = v.y - mu, d2 = v.z - mu, d3 = v.w - mu;
  float ss = d0 * d0 + d1 * d1 + d2 * d2 + d3 * d3;
#pragma unroll
  for (int o = 32; o; o >>= 1) ss += __shfl_xor(ss, o);
  if (lane == 0) red2[w] = ss;
  __syncthreads();
  const float var = (red2[0] + red2[1] + red2[2] + red2[3]) * (1.0f / 1024.0f);
  const float rs = rsqrtf(var + 1e-6f);
  const float4 g = *(const float4*)(gamma + t * 4);
  const float4 b = *(const float4*)(beta + t * 4);
  float4 o;
  o.x = d0 * rs * g.x + b.x;
  o.y = d1 * rs * g.y + b.y;
  o.z = d2 * rs * g.z + b.z;
  o.w = d3 * rs * g.w + b.w;
  *(float4*)(rp + t * 4) = o;
}

extern "C" void kernel_launch(void* const* d_in, const int* in_sizes, int n_in,
                              void* d_out, int out_size, void* d_ws, size_t ws_size,
                              hipStream_t stream) {
  const float* query = (const float*)d_in[0];
  const float* key   = (const float*)d_in[1];
  const float* value = (const float*)d_in[2];
  const float* Wq = (const float*)d_in[3];
  const float* bq = (const float*)d_in[4];
  const float* Wk = (const float*)d_in[5];
  const float* bk = (const float*)d_in[6];
  const float* Wv = (const float*)d_in[7];
  const float* bv = (const float*)d_in[8];
  const float* Wo = (const float*)d_in[9];
  const float* bo = (const float*)d_in[10];
  const float* gamma = (const float*)d_in[11];
  const float* beta  = (const float*)d_in[12];
  float* out = (float*)d_out;

  char* ws = (char*)d_ws;
  const size_t XSZ = (size_t)NBATCH * SEQ * E_DIM * 2;  // 16 MiB
  const size_t WSZ = (size_t)E_DIM * E_DIM * 2;         // 2 MiB
  const size_t B2  = 3 * XSZ;                           // 48 MiB boundary

  bf16_t* Xq  = (bf16_t*)(ws + 0);
  bf16_t* Xk  = (bf16_t*)(ws + XSZ);
  bf16_t* Xv  = (bf16_t*)(ws + 2 * XSZ);
  bf16_t* SC  = (bf16_t*)(ws + 0);   // bf16 scores overlay the dead X buffers
  bf16_t* Wqb = (bf16_t*)(ws + B2);
  bf16_t* Wkb = (bf16_t*)(ws + B2 + WSZ);
  bf16_t* Wvb = (bf16_t*)(ws + B2 + 2 * WSZ);
  bf16_t* Wob = (bf16_t*)(ws + B2 + 3 * WSZ);
  bf16_t* Qb  = (bf16_t*)(ws + B2 + 4 * WSZ);
  bf16_t* Kb  = (bf16_t*)(ws + B2 + 4 * WSZ + XSZ);
  bf16_t* Vt  = (bf16_t*)(ws + B2 + 4 * WSZ + 2 * XSZ);
  bf16_t* Ctx = (bf16_t*)(ws + B2 + 4 * WSZ + 3 * XSZ);

  const int NTOK = NBATCH * SEQ;  // 8192
  const int SMB = 65536;

  hipFuncSetAttribute((const void*)k_gemm3<0>, hipFuncAttributeMaxDynamicSharedMemorySize, SMB);
  hipFuncSetAttribute((const void*)k_gemm3<1>, hipFuncAttributeMaxDynamicSharedMemorySize, SMB);
  hipFuncSetAttribute((const void*)k_gemm3<2>, hipFuncAttributeMaxDynamicSharedMemorySize, SMB);

  // 1) casts
  k_cast<<<dim3(NTOK * E_DIM / 2048), 256, 0, stream>>>(query, Xq);
  k_cast<<<dim3(NTOK * E_DIM / 2048), 256, 0, stream>>>(key, Xk);
  k_cast<<<dim3(NTOK * E_DIM / 2048), 256, 0, stream>>>(value, Xv);
  k_cast<<<dim3(E_DIM * E_DIM / 2048), 256, 0, stream>>>(Wq, Wqb);
  k_cast<<<dim3(E_DIM * E_DIM / 2048), 256, 0, stream>>>(Wk, Wkb);
  k_cast<<<dim3(E_DIM * E_DIM / 2048), 256, 0, stream>>>(Wv, Wvb);
  k_cast<<<dim3(E_DIM * E_DIM / 2048), 256, 0, stream>>>(Wo, Wob);

  // 2) projections (grid 64x8 = 512 wg, 2 blocks/CU)
  k_gemm3<1><<<512, 256, SMB, stream>>>(
      Xq, E_DIM, 0, Wqb, E_DIM, 0, Qb, E_DIM, 0, E_DIM, 1.0f, bq, nullptr, 64, 8);
  k_gemm3<1><<<512, 256, SMB, stream>>>(
      Xk, E_DIM, 0, Wkb, E_DIM, 0, Kb, E_DIM, 0, E_DIM, 1.0f, bk, nullptr, 64, 8);
  k_gemm3<2><<<512, 256, SMB, stream>>>(
      Xv, E_DIM, 0, Wvb, E_DIM, 0, Vt, 0, 0, E_DIM, 1.0f, bv, nullptr, 64, 8);

  // 3) scores = Q K^T / 32 -> bf16 (grid 16x16x4 = 1024 wg)
  k_gemm3<1><<<1024, 256, SMB, stream>>>(
      Qb, E_DIM, (long)SEQ * E_DIM, Kb, E_DIM, (long)SEQ * E_DIM,
      SC, SEQ, (long)SEQ * SEQ, E_DIM, 0.03125f, nullptr, nullptr, 16, 16);

  // 4) softmax rows -> bf16 P in place
  k_softmax_bf<<<dim3(NTOK), 256, 0, stream>>>(SC);

  // 5) ctx = P @ V (B = Vt in [N][K] layout; grid 16x8x4 = 512 wg)
  k_gemm3<1><<<512, 256, SMB, stream>>>(
      SC, SEQ, (long)SEQ * SEQ, Vt, SEQ, (long)E_DIM * SEQ,
      Ctx, E_DIM, (long)SEQ * E_DIM, SEQ, 1.0f, nullptr, nullptr, 16, 8);

  // 6) out = ctx Wo^T + bo + residual (f32 into d_out; grid 64x8 = 512)
  k_gemm3<0><<<512, 256, SMB, stream>>>(
      Ctx, E_DIM, 0, Wob, E_DIM, 0, out, E_DIM, 0, E_DIM, 1.0f, bo, query, 64, 8);

  // 7) layernorm in-place
  k_layernorm<<<dim3(NTOK), 256, 0, stream>>>(out, gamma, beta);
}